// Round 4
// baseline (150.741 us; speedup 1.0000x reference)
//
#include <hip/hip_runtime.h>
#include <hip/hip_bf16.h>

#define N2    16384
#define NHALF 8192
#define KDIM  128
#define BROW  128      // rows per block
#define BCOL  128      // B-tile cols per iteration (32 KB/tile -> 2 blocks/CU)
#define NQUARTER 4096  // cols per block (grid = 128 row-tiles x 4 col-quarters)
#define NITER (NQUARTER / BCOL)   // 32

using bf16x8 = __attribute__((ext_vector_type(8))) short;
using f32x4  = __attribute__((ext_vector_type(4))) float;

#if __has_builtin(__builtin_amdgcn_exp2f)
#define EXP2F(x) __builtin_amdgcn_exp2f(x)
#else
#define EXP2F(x) exp2f(x)
#endif
#if __has_builtin(__builtin_amdgcn_logf)
#define LOG2F(x) __builtin_amdgcn_logf(x)
#else
#define LOG2F(x) log2f(x)
#endif

// exp(2*dot) == exp2(dot * 2*log2(e)); fold sqrt(2*log2(e)) into z at convert
// time so the MFMA result is already in exp2 domain (epilogue = bare v_exp).
#define PRESCALE 1.6986436005760381f   // sqrt(2*log2(e))

typedef const __attribute__((address_space(1))) void* gas_ptr;
typedef __attribute__((address_space(3))) void* las_ptr;

__device__ __forceinline__ unsigned short f2bf(float f) {
  unsigned u = __float_as_uint(f);
  u += 0x7fffu + ((u >> 16) & 1u);   // RNE
  return (unsigned short)(u >> 16);
}

// ---- K1: f32 -> bf16 conversion with PRESCALE (z -> zb) + zero S and out ----
__global__ void k_convert(const float* __restrict__ z, unsigned short* __restrict__ zb,
                          float* __restrict__ S, float* __restrict__ out) {
  int i = blockIdx.x * blockDim.x + threadIdx.x;  // over N2*KDIM/4
  if (i < N2) S[i] = 0.f;
  if (i == 0) out[0] = 0.f;
  float4 v = reinterpret_cast<const float4*>(z)[i];
  ushort4 o;
  o.x = f2bf(v.x * PRESCALE); o.y = f2bf(v.y * PRESCALE);
  o.z = f2bf(v.z * PRESCALE); o.w = f2bf(v.w * PRESCALE);
  reinterpret_cast<ushort4*>(zb)[i] = o;
}

// ---- K2: fused sim -> exp -> row sums (diagonal masked) ----
// grid = 512: (row-tile bt = bx>>2) x (col quarter = bx&3)
// block = 512 = 8 waves: 2 row-groups x 4 col-strips(32), 64x32 per wave.
// A (64 rows x K=128 per wave) lives in registers for the whole kernel.
// B tiles: double-buffered LDS (2 x 32 KB = 64 KB/block -> 2 blocks/CU; the
// R3 128 KB footprint capped the CU at 1 block = 21% occupancy), filled by
// async global_load_lds DMA with the XOR granule swizzle applied on *source*
// addresses (DMA LDS dest is lane-linear). Swizzle verified conflict-free
// (R2/R3: SQ_LDS_BANK_CONFLICT == 0).
// __launch_bounds__ 2nd arg behaves as min BLOCKS/CU (R2 evidence: N=4 ->
// 64 VGPRs; N=2 -> 116). Keep N=2 -> VGPR cap 128, registers already fit.
// acc restructured per-n-tile (acc[4], not acc[4][4]) to stay under the cap.
__global__ __launch_bounds__(512, 2) void k_main(const unsigned short* __restrict__ zb,
                                                 float* __restrict__ S) {
  __shared__ __align__(16) unsigned short Bs[2][BCOL * KDIM];  // 2 x 32 KiB
  const int t    = threadIdx.x;
  const int w    = t >> 6;
  const int l    = t & 63;
  const int q    = l >> 4;    // quad within wave
  const int c15  = l & 15;
  const int bt      = blockIdx.x >> 2;
  const int quarter = blockIdx.x & 3;
  const int mg   = w >> 2;    // which 64-row group
  const int ns   = w & 3;     // which 32-col strip
  const int rbase = bt * BROW + mg * 64;

  // Per-lane DMA source byte offsets (within one 32 KB tile), 4 issues/wave.
  // Physical granule p = (w*4+j)*64 + l ; row=p>>4, pg=p&15 ; data granule
  // k8 = pg ^ (row&15).
  int srcoff[4];
#pragma unroll
  for (int j = 0; j < 4; ++j) {
    int p   = (w * 4 + j) * 64 + l;
    int row = p >> 4;
    int pg  = p & 15;
    int k8  = pg ^ (row & 15);
    srcoff[j] = (row * 16 + k8) * 16;   // bytes
  }

  const char* tile0 = (const char*)zb + (size_t)(quarter * NQUARTER) * KDIM * 2;

  // Kick off DMA for tile 0 into buffer 0.
#pragma unroll
  for (int j = 0; j < 4; ++j)
    __builtin_amdgcn_global_load_lds((gas_ptr)(tile0 + srcoff[j]),
                                     (las_ptr)(&Bs[0][(w * 4 + j) * 512]), 16, 0, 0);

  // A fragments: a-frag layout (16x16x32): lane holds A[m=lane&15][k=q*8+j]
  bf16x8 afr[4][4];
#pragma unroll
  for (int m = 0; m < 4; ++m) {
    const unsigned short* ap = zb + (size_t)(rbase + m * 16 + c15) * KDIM + q * 8;
#pragma unroll
    for (int s = 0; s < 4; ++s)
      afr[m][s] = *reinterpret_cast<const bf16x8*>(ap + s * 32);
  }

  float rowsum[4][4];
#pragma unroll
  for (int m = 0; m < 4; ++m)
#pragma unroll
    for (int r = 0; r < 4; ++r) rowsum[m][r] = 0.f;

  for (int it = 0; it < NITER; ++it) {
    const int buf = it & 1;
    const int C0  = quarter * NQUARTER + it * BCOL;
    // Barrier's vmcnt(0) drain completes tile `it`'s DMA; barrier itself
    // guarantees all waves finished reading buf^1 last iteration.
    __syncthreads();

    // Prefetch tile it+1 into the other buffer; completes during compute.
    if (it + 1 < NITER) {
      const char* src = tile0 + (size_t)(it + 1) * BCOL * KDIM * 2;
#pragma unroll
      for (int j = 0; j < 4; ++j)
        __builtin_amdgcn_global_load_lds((gas_ptr)(src + srcoff[j]),
                                         (las_ptr)(&Bs[buf ^ 1][(w * 4 + j) * 512]), 16, 0, 0);
    }

#pragma unroll
    for (int nt = 0; nt < 2; ++nt) {
      const int rloc = ns * 32 + nt * 16 + c15;   // B row within tile
      f32x4 acc[4];
#pragma unroll
      for (int m = 0; m < 4; ++m) acc[m] = (f32x4){0.f, 0.f, 0.f, 0.f};
#pragma unroll
      for (int s = 0; s < 4; ++s) {
        int pg = (s * 4 + q) ^ (rloc & 15);
        bf16x8 bfr = *reinterpret_cast<const bf16x8*>(&Bs[buf][rloc * KDIM + pg * 8]);
#pragma unroll
        for (int m = 0; m < 4; ++m)
          acc[m] = __builtin_amdgcn_mfma_f32_16x16x32_bf16(afr[m][s], bfr, acc[m], 0, 0, 0);
      }
      // epilogue: exp2 + row-sum; diagonal masked (wave-uniform per m-tile)
      const int gcol = C0 + ns * 32 + nt * 16;
#pragma unroll
      for (int m = 0; m < 4; ++m) {
        if (gcol == rbase + m * 16) {
#pragma unroll
          for (int r = 0; r < 4; ++r) {
            float e = EXP2F(acc[m][r]);
            if (c15 == q * 4 + r) e = 0.f;  // sim[i][i]
            rowsum[m][r] += e;
          }
        } else {
#pragma unroll
          for (int r = 0; r < 4; ++r) rowsum[m][r] += EXP2F(acc[m][r]);
        }
      }
    }
  }

  // reduce across 16 column-lanes (xor 1,2,4,8 stay within quads), then one
  // atomicAdd per row-partial (4 per S element across the col-quarters)
#pragma unroll
  for (int m = 0; m < 4; ++m)
#pragma unroll
    for (int r = 0; r < 4; ++r) {
      float v = rowsum[m][r];
      v += __shfl_xor(v, 1);
      v += __shfl_xor(v, 2);
      v += __shfl_xor(v, 4);
      v += __shfl_xor(v, 8);
      if (c15 == 0) atomicAdd(&S[rbase + m * 16 + q * 4 + r], v);
    }
}

// ---- K3: loss_i = log(S_i) - 2*z_i.z_pair(i); mean into out ----
__global__ void k_final(const float* __restrict__ z, const float* __restrict__ S,
                        float* __restrict__ out) {
  __shared__ float red[256];
  int t = threadIdx.x;
  int i = blockIdx.x * 256 + t;
  int j = i ^ NHALF;  // positive pair index
  const float4* zi = reinterpret_cast<const float4*>(z + (size_t)i * KDIM);
  const float4* zj = reinterpret_cast<const float4*>(z + (size_t)j * KDIM);
  float dot = 0.f;
#pragma unroll
  for (int k = 0; k < KDIM / 4; ++k) {
    float4 a = zi[k], b = zj[k];
    dot += a.x * b.x + a.y * b.y + a.z * b.z + a.w * b.w;
  }
  float loss = LOG2F(S[i]) * 0.69314718055994531f - 2.f * dot;
  red[t] = loss;
  __syncthreads();
  for (int o = 128; o > 0; o >>= 1) {
    if (t < o) red[t] += red[t + o];
    __syncthreads();
  }
  if (t == 0) atomicAdd(out, red[0] * (1.f / N2));
}

extern "C" void kernel_launch(void* const* d_in, const int* in_sizes, int n_in,
                              void* d_out, int out_size, void* d_ws, size_t ws_size,
                              hipStream_t stream) {
  const float* z = (const float*)d_in[0];
  float* out = (float*)d_out;
  unsigned short* zb = (unsigned short*)d_ws;                       // 4 MB bf16 copy of z
  float* S = (float*)((char*)d_ws + (size_t)N2 * KDIM * 2);         // 64 KB row sums

  k_convert<<<(N2 * KDIM / 4) / 256, 256, 0, stream>>>(z, zb, S, out);
  k_main<<<512, 512, 0, stream>>>(zb, S);
  k_final<<<N2 / 256, 256, 0, stream>>>(z, S, out);
}